// Round 8
// baseline (848.046 us; speedup 1.0000x reference)
//
#include <hip/hip_runtime.h>
#include <stdint.h>

#define T_DIM 512
#define B_DIM 256
#define OBS_DIM 128
#define H_DIM 256
#define TB (T_DIM * B_DIM)

typedef _Float16 f16;
typedef __attribute__((ext_vector_type(8))) _Float16 f16x8;
typedef __attribute__((ext_vector_type(4))) float f32x4;

union H2U { f16 h[2]; uint32_t u; };

__device__ __forceinline__ f32x4 fz4() { f32x4 v; v[0]=0.f; v[1]=0.f; v[2]=0.f; v[3]=0.f; return v; }
__device__ __forceinline__ float sigm(float x) {
  float e = __expf(-x);
  return __builtin_amdgcn_rcpf(1.f + e);
}
__device__ __forceinline__ float tanh_f(float x) {
  float e = __expf(-2.f * x);
  return (1.f - e) * __builtin_amdgcn_rcpf(1.f + e);
}

// ---------------------------------------------------------------------------
// K0: weights -> f16. encW 32768 | Wih 196608 | head 8192 (rows0-15 pol,16 val)
// ---------------------------------------------------------------------------
__global__ void k_prep(const float* __restrict__ encW, const float* __restrict__ Wih,
                       const float* __restrict__ polW, const float* __restrict__ valW,
                       f16* __restrict__ encW_h, f16* __restrict__ Wih_h,
                       f16* __restrict__ headW_h) {
  int e = blockIdx.x * 256 + threadIdx.x;
  if (e < 32768) { encW_h[e] = (f16)encW[e]; return; }
  e -= 32768;
  if (e < 196608) { Wih_h[e] = (f16)Wih[e]; return; }
  e -= 196608;
  if (e < 8192) {
    int r = e >> 8, c = e & 255;
    float v = (r < 16) ? polW[r * 256 + c] : (r == 16 ? valW[c] : 0.f);
    headW_h[e] = (f16)v;
  }
}

// ---------------------------------------------------------------------------
// K1: x = tanh(obs @ enc_W^T + enc_b) -> f16 into xgi. M-tile 128, grid 1024.
// ---------------------------------------------------------------------------
__global__ __launch_bounds__(512) void k_enc(const float* __restrict__ obs,
                                             const f16* __restrict__ encW_h,
                                             const float* __restrict__ enc_b,
                                             f16* __restrict__ xgi) {
  __shared__ f16 lA[128 * 64];  // 16KB [128 rows][64 k] swizzled
  __shared__ f16 lB[256 * 64];  // 32KB [256 n][64 k] swizzled
  const int tid = threadIdx.x, lane = tid & 63, w = tid >> 6;
  const int m0 = blockIdx.x * 128;
  f32x4 acc[16];
#pragma unroll
  for (int i = 0; i < 16; i++) acc[i] = fz4();

  for (int kc = 0; kc < 2; kc++) {
    const int k0c = kc * 64;
#pragma unroll
    for (int i = 0; i < 4; i++) {
      int c = tid + i * 512;
      int r = c >> 4, kk = (c & 15) * 4;
      float4 v = *(const float4*)(obs + (size_t)(m0 + r) * OBS_DIM + k0c + kk);
      H2U a, b;
      a.h[0] = (f16)v.x; a.h[1] = (f16)v.y; b.h[0] = (f16)v.z; b.h[1] = (f16)v.w;
      uint32_t off = ((uint32_t)(r * 128 + kk * 2)) ^ (((uint32_t)(r & 7)) << 4);
      uint2 p; p.x = a.u; p.y = b.u;
      *(uint2*)((char*)lA + off) = p;
    }
#pragma unroll
    for (int i = 0; i < 4; i++) {
      int c = tid + i * 512;
      int r = c >> 3, kk = (c & 7) * 8;
      f16x8 v = *(const f16x8*)(encW_h + (size_t)r * OBS_DIM + k0c + kk);
      uint32_t off = ((uint32_t)(r * 128 + kk * 2)) ^ (((uint32_t)(r & 7)) << 4);
      *(f16x8*)((char*)lB + off) = v;
    }
    __syncthreads();
#pragma unroll
    for (int ks = 0; ks < 2; ks++) {
      const int ar = w * 16 + (lane & 15);
      const int kofs = (ks * 32 + ((lane >> 4) << 3)) * 2;
      uint32_t aoff = ((uint32_t)(ar * 128 + kofs)) ^ (((uint32_t)(ar & 7)) << 4);
      f16x8 af = *(const f16x8*)((char*)lA + aoff);
#pragma unroll
      for (int i = 0; i < 16; i++) {
        const int br = i * 16 + (lane & 15);
        uint32_t boff = ((uint32_t)(br * 128 + kofs)) ^ (((uint32_t)(br & 7)) << 4);
        f16x8 bfr = *(const f16x8*)((char*)lB + boff);
        acc[i] = __builtin_amdgcn_mfma_f32_16x16x32_f16(af, bfr, acc[i], 0, 0, 0);
      }
    }
    __syncthreads();
  }
  const int mrow = m0 + w * 16 + ((lane >> 4) << 2);
#pragma unroll
  for (int i = 0; i < 16; i++) {
    const int col = i * 16 + (lane & 15);
    const float bb = enc_b[col];
#pragma unroll
    for (int r = 0; r < 4; r++) {
      float s = acc[i][r] + bb;
      xgi[(size_t)(mrow + r) * H_DIM + col] = (f16)tanh_f(s);
    }
  }
}

// ---------------------------------------------------------------------------
// K2: all 3 gates fused: gi = x @ W_ih^T + bias. M-tile 64, N=768, grid 2048.
// r,z -> gi_rz f16 [TB][256][2] INTERLEAVED; n -> xgi [TB][256].
// ---------------------------------------------------------------------------
__global__ __launch_bounds__(512) void k_gi3(const f16* __restrict__ xgi_r,
                                             const f16* __restrict__ Wih_h,
                                             const float* __restrict__ b_ih,
                                             const float* __restrict__ b_hh,
                                             f16* __restrict__ gi_rz,
                                             f16* __restrict__ xgi_w) {
  __shared__ f16 lA[64 * 64];    // 8KB
  __shared__ f16 lB[768 * 64];   // 96KB
  const int tid = threadIdx.x, lane = tid & 63, w = tid >> 6;
  const int m0 = blockIdx.x * 64;
  const int mstrip = w >> 1, nh = w & 1;
  f32x4 acc[24];
#pragma unroll
  for (int i = 0; i < 24; i++) acc[i] = fz4();

  for (int kc = 0; kc < 4; kc++) {
    const int k0c = kc * 64;
    {
      int r = tid >> 3, kk = (tid & 7) * 8;
      f16x8 v = *(const f16x8*)(xgi_r + (size_t)(m0 + r) * H_DIM + k0c + kk);
      uint32_t off = ((uint32_t)(r * 128 + kk * 2)) ^ (((uint32_t)(r & 7)) << 4);
      *(f16x8*)((char*)lA + off) = v;
    }
#pragma unroll
    for (int i = 0; i < 12; i++) {
      int c = tid + i * 512;
      int r = c >> 3, kk = (c & 7) * 8;
      f16x8 v = *(const f16x8*)(Wih_h + (size_t)r * H_DIM + k0c + kk);
      uint32_t off = ((uint32_t)(r * 128 + kk * 2)) ^ (((uint32_t)(r & 7)) << 4);
      *(f16x8*)((char*)lB + off) = v;
    }
    __syncthreads();
#pragma unroll
    for (int ks = 0; ks < 2; ks++) {
      const int ar = mstrip * 16 + (lane & 15);
      const int kofs = (ks * 32 + ((lane >> 4) << 3)) * 2;
      uint32_t aoff = ((uint32_t)(ar * 128 + kofs)) ^ (((uint32_t)(ar & 7)) << 4);
      f16x8 af = *(const f16x8*)((char*)lA + aoff);
#pragma unroll
      for (int i = 0; i < 24; i++) {
        const int br = nh * 384 + i * 16 + (lane & 15);
        uint32_t boff = ((uint32_t)(br * 128 + kofs)) ^ (((uint32_t)(br & 7)) << 4);
        f16x8 bfr = *(const f16x8*)((char*)lB + boff);
        acc[i] = __builtin_amdgcn_mfma_f32_16x16x32_f16(af, bfr, acc[i], 0, 0, 0);
      }
    }
    __syncthreads();
  }
  const int mrow = m0 + mstrip * 16 + ((lane >> 4) << 2);
#pragma unroll
  for (int i = 0; i < 24; i++) {
    const int col = nh * 384 + i * 16 + (lane & 15);
    float bb = b_ih[col];
    if (col < 512) bb += b_hh[col];
#pragma unroll
    for (int r = 0; r < 4; r++) {
      float s = acc[i][r] + bb;
      size_t tb = (size_t)(mrow + r);
      if (col < 512) gi_rz[tb * 512 + (size_t)((col & 255) * 2 + (col >> 8))] = (f16)s;
      else           xgi_w[tb * 256 + (col - 512)] = (f16)s;
    }
  }
}

// ---------------------------------------------------------------------------
// K3: GRU scan v8. grid(128) x block 1024 (16 waves, 4 waves/SIMD). WG owns
// 2 batch rows. Wave w owns cols [16w,16w+16) of ALL 3 gates (triplet ->
// redistribution stays wave-local). 24 MFMA/wave/step -> 96/SIMD (floor),
// but 4 waves/SIMD pack tails into each other's MFMA bursts.
//  - h buffer is just 2 rows; A-frag lanes re-read row (lane&1... &15)&1:
//    rows 2-15 of A only affect D rows 2-15 which we never read.
//  - weights: ks 0..6 in regs (21 frags, 84 VGPR), ks 7 in LDS (hard
//    128-VGPR/wave cap at 16 waves/CU).
//  - raw lgkmcnt+s_barrier once per step; setprio around MFMA; gi prefetch
//    distance 1; outs overwrites gi_n in place (same lane/address).
// ---------------------------------------------------------------------------
__global__ __launch_bounds__(1024, 4) void k_scan(const float* __restrict__ Whh,
                                                  const float* __restrict__ b_hh,
                                                  const float* __restrict__ done,
                                                  const uint32_t* __restrict__ gi_rz,
                                                  f16* xgi) {
  __shared__ f16 h_l[2][2][264];        // 2KB [buf][row][k]
  __shared__ float gh_l[16][3][16][2];  // 6KB [wave][g][col16][row]
  __shared__ float done_l[T_DIM][2];    // 4KB
  __shared__ f16 wb_l[16 * 3 * 64 * 8]; // 48KB ks=7 B-frags, lane-contiguous
  const int tid = threadIdx.x, lane = tid & 63, w = tid >> 6;
  const int b0 = blockIdx.x * 2;

  for (int i = tid; i < 2 * 2 * 264; i += 1024) ((f16*)h_l)[i] = (f16)0.f;
  {
    int t = tid >> 1, j = tid & 1;
    done_l[t][j] = done[(size_t)t * B_DIM + b0 + j];
  }

  // W_hh -> f16 B-frags. Wave w, gate g: W rows g*256 + w*16 + (lane&15).
  f16x8 wf[3][7];
#pragma unroll
  for (int g = 0; g < 3; g++) {
    const int rowW = g * 256 + w * 16 + (lane & 15);
    const float* wrow = Whh + (size_t)rowW * H_DIM;
#pragma unroll
    for (int ks = 0; ks < 8; ks++) {
      const int k0 = ks * 32 + ((lane >> 4) << 3);
      float4 a = *(const float4*)(wrow + k0);
      float4 b = *(const float4*)(wrow + k0 + 4);
      f16x8 f;
      f[0] = (f16)a.x; f[1] = (f16)a.y; f[2] = (f16)a.z; f[3] = (f16)a.w;
      f[4] = (f16)b.x; f[5] = (f16)b.y; f[6] = (f16)b.z; f[7] = (f16)b.w;
      if (ks < 7) wf[g][ks] = f;
      else *(f16x8*)&wb_l[((w * 3 + g) * 64 + lane) * 8] = f;
    }
  }
  // C-in seeds: zero for r,z; splat b_hh_n for n gate (valid in lanes 0-15)
  f32x4 zs = fz4();
  f32x4 ns;
  {
    const float bv = b_hh[512 + w * 16 + (lane & 15)];
    ns[0] = bv; ns[1] = bv; ns[2] = bv; ns[3] = bv;
  }

  // A-frag bases: broadcast rows 0/1 (rows 2-15 of A only affect unread D rows)
  const int koff = (lane >> 4) << 3;
  const f16* hA = &h_l[0][lane & 1][koff];
  const f16* hB = &h_l[1][lane & 1][koff];
  const f16* wrd = &wb_l[(w * 3 * 64 + lane) * 8];

  // phase-B assignment: lanes 0-31, col = 16w + (lane&15), row = lane>>4
  const int colB = w * 16 + (lane & 15);
  const int rowB = (lane >> 4) & 1;
  const bool doB = (lane < 32);
  const float bhhn_b = b_hh[512 + colB];
  const size_t baseB = ((size_t)b0 + rowB) * 256 + colB;
  const uint32_t* prz = gi_rz + baseB;
  f16* pgn = xgi + baseB;   // gi_n read AND outs write (same address)
  uint32_t rz_nx = 0; uint32_t gn_nx = 0;
  if (doB) { rz_nx = *prz; gn_nx = (uint32_t)*(const uint16_t*)pgn; }
  __syncthreads();

  for (int t = 0; t < T_DIM; t++) {
    const uint32_t rz_cu = rz_nx;
    const uint32_t gn_cu = gn_nx;
    if (doB && t != T_DIM - 1) {
      prz += 65536;
      rz_nx = prz[0];
      gn_nx = (uint32_t)*(const uint16_t*)(pgn + 65536);
    }
    const f16* hrd = (t & 1) ? hB : hA;

    f32x4 a0, a1, a2;
    __builtin_amdgcn_s_setprio(1);
    {
      const f16x8 af = *(const f16x8*)&hrd[0];
      a0 = __builtin_amdgcn_mfma_f32_16x16x32_f16(af, wf[0][0], zs, 0, 0, 0);
      a1 = __builtin_amdgcn_mfma_f32_16x16x32_f16(af, wf[1][0], zs, 0, 0, 0);
      a2 = __builtin_amdgcn_mfma_f32_16x16x32_f16(af, wf[2][0], ns, 0, 0, 0);
    }
#pragma unroll
    for (int ks = 1; ks < 7; ks++) {
      const f16x8 af = *(const f16x8*)&hrd[ks * 32];
      a0 = __builtin_amdgcn_mfma_f32_16x16x32_f16(af, wf[0][ks], a0, 0, 0, 0);
      a1 = __builtin_amdgcn_mfma_f32_16x16x32_f16(af, wf[1][ks], a1, 0, 0, 0);
      a2 = __builtin_amdgcn_mfma_f32_16x16x32_f16(af, wf[2][ks], a2, 0, 0, 0);
    }
    {
      const f16x8 af = *(const f16x8*)&hrd[7 * 32];
      const f16x8 b0f = *(const f16x8*)&wrd[0];
      const f16x8 b1f = *(const f16x8*)&wrd[512];
      const f16x8 b2f = *(const f16x8*)&wrd[1024];
      a0 = __builtin_amdgcn_mfma_f32_16x16x32_f16(af, b0f, a0, 0, 0, 0);
      a1 = __builtin_amdgcn_mfma_f32_16x16x32_f16(af, b1f, a1, 0, 0, 0);
      a2 = __builtin_amdgcn_mfma_f32_16x16x32_f16(af, b2f, a2, 0, 0, 0);
    }
    __builtin_amdgcn_s_setprio(0);

    // wave-local redistribution: lanes 0-15 hold batch rows 0,1 in regs 0,1
    if (lane < 16) {
      float2 v0; v0.x = a0[0]; v0.y = a0[1];
      *(float2*)&gh_l[w][0][lane][0] = v0;
      float2 v1; v1.x = a1[0]; v1.y = a1[1];
      *(float2*)&gh_l[w][1][lane][0] = v1;
      float2 v2; v2.x = a2[0]; v2.y = a2[1];
      *(float2*)&gh_l[w][2][lane][0] = v2;
    }
    __builtin_amdgcn_sched_barrier(0);
    asm volatile("s_waitcnt lgkmcnt(0)" ::: "memory");
    __builtin_amdgcn_sched_barrier(0);

    if (doB) {
      const int cl = lane & 15;
      const float ghr = gh_l[w][0][cl][rowB];
      const float ghz = gh_l[w][1][cl][rowB];
      const float ghn = gh_l[w][2][cl][rowB];
      H2U u; u.u = rz_cu;
      H2U gu; gu.u = gn_cu;
      const float rr = sigm((float)u.h[0] + ghr);
      const float zz = sigm((float)u.h[1] + ghz);
      const float nn = tanh_f((float)gu.h[0] + rr * ghn);
      const float hp = (float)h_l[t & 1][rowB][colB];
      const float ho = nn + zz * (hp - nn);
      *pgn = (f16)ho;  pgn += 65536;                 // outs (same slot as gi_n)
      const float dn = done_l[t][rowB];              // masks h going into t+1
      h_l[(t & 1) ^ 1][rowB][colB] = (f16)((dn != 0.f) ? 0.f : ho);
    }

    __builtin_amdgcn_sched_barrier(0);
    asm volatile("s_waitcnt lgkmcnt(0)" ::: "memory");
    __builtin_amdgcn_s_barrier();
    __builtin_amdgcn_sched_barrier(0);
  }
}

// ---------------------------------------------------------------------------
// K4: heads. M-tile 64, N=32 (16 pol + 1 val + pad), grid 2048, block 256.
// ---------------------------------------------------------------------------
__global__ __launch_bounds__(256) void k_heads(const f16* __restrict__ outs,
                                               const f16* __restrict__ headW_h,
                                               const float* __restrict__ pol_b,
                                               const float* __restrict__ val_b,
                                               float* __restrict__ out) {
  __shared__ f16 lA[64 * 256];  // 32KB swizzled
  __shared__ f16 lB[32 * 256];  // 16KB
  const int tid = threadIdx.x, lane = tid & 63, w = tid >> 6;
  const int m0 = blockIdx.x * 64;
#pragma unroll
  for (int i = 0; i < 8; i++) {
    int c = tid + i * 256;
    int r = c >> 5, o = (c & 31) * 8;
    f16x8 v = *(const f16x8*)(outs + (size_t)(m0 + r) * H_DIM + o);
    uint32_t off = ((uint32_t)(r * 512 + o * 2)) ^ (((uint32_t)(r & 7)) << 4);
    *(f16x8*)((char*)lA + off) = v;
  }
#pragma unroll
  for (int i = 0; i < 4; i++) {
    int c = tid + i * 256;
    int r = c >> 5, o = (c & 31) * 8;
    f16x8 v = *(const f16x8*)(headW_h + (size_t)r * H_DIM + o);
    uint32_t off = ((uint32_t)(r * 512 + o * 2)) ^ (((uint32_t)(r & 7)) << 4);
    *(f16x8*)((char*)lB + off) = v;
  }
  __syncthreads();
  f32x4 acc[2];
  acc[0] = fz4(); acc[1] = fz4();
#pragma unroll
  for (int ks = 0; ks < 8; ks++) {
    const int ar = w * 16 + (lane & 15);
    const int kofs = (ks * 32 + ((lane >> 4) << 3)) * 2;
    uint32_t aoff = ((uint32_t)(ar * 512 + kofs)) ^ (((uint32_t)(ar & 7)) << 4);
    f16x8 af = *(const f16x8*)((char*)lA + aoff);
#pragma unroll
    for (int nt = 0; nt < 2; nt++) {
      const int br = nt * 16 + (lane & 15);
      uint32_t boff = ((uint32_t)(br * 512 + kofs)) ^ (((uint32_t)(br & 7)) << 4);
      f16x8 bfr = *(const f16x8*)((char*)lB + boff);
      acc[nt] = __builtin_amdgcn_mfma_f32_16x16x32_f16(af, bfr, acc[nt], 0, 0, 0);
    }
  }
  const int n = lane & 15;
  const float pb = pol_b[n];
  const float vb = val_b[0];
#pragma unroll
  for (int r = 0; r < 4; r++) {
    const int mrow = m0 + w * 16 + ((lane >> 4) << 2) + r;
    out[(size_t)mrow * 16 + n] = acc[0][r] + pb;
    if (n == 0) out[(size_t)TB * 16 + mrow] = acc[1][r] + vb;
  }
}

// ---------------------------------------------------------------------------
// Workspace layout (192.5 MiB total):
//   [0,128Mi)        gi_rz f16 [TB][256][2]  (r,z interleaved)
//   [128Mi,192Mi)    xgi  f16 [TB][256]  (x -> gi_n -> outs, race-free)
//   [192Mi,+475KB)   encW_h | Wih_h | headW_h
// ---------------------------------------------------------------------------
extern "C" void kernel_launch(void* const* d_in, const int* in_sizes, int n_in,
                              void* d_out, int out_size, void* d_ws, size_t ws_size,
                              hipStream_t stream) {
  (void)in_sizes; (void)n_in; (void)out_size; (void)ws_size;
  const float* obs   = (const float*)d_in[0];
  const float* done  = (const float*)d_in[1];
  const float* encW  = (const float*)d_in[2];
  const float* enc_b = (const float*)d_in[3];
  const float* Wih   = (const float*)d_in[4];
  const float* Whh   = (const float*)d_in[5];
  const float* b_ih  = (const float*)d_in[6];
  const float* b_hh  = (const float*)d_in[7];
  const float* polW  = (const float*)d_in[8];
  const float* pol_b = (const float*)d_in[9];
  const float* valW  = (const float*)d_in[10];
  const float* val_b = (const float*)d_in[11];

  char* ws = (char*)d_ws;
  f16* gi_rz   = (f16*)ws;
  f16* xgi     = (f16*)(ws + (size_t)134217728);
  f16* encW_h  = (f16*)(ws + (size_t)201326592);
  f16* Wih_h   = encW_h + 32768;
  f16* headW_h = Wih_h + 196608;
  float* outp  = (float*)d_out;

  k_prep<<<dim3(928), dim3(256), 0, stream>>>(encW, Wih, polW, valW, encW_h, Wih_h, headW_h);
  k_enc<<<dim3(1024), dim3(512), 0, stream>>>(obs, encW_h, enc_b, xgi);
  k_gi3<<<dim3(2048), dim3(512), 0, stream>>>(xgi, Wih_h, b_ih, b_hh, gi_rz, xgi);
  k_scan<<<dim3(128), dim3(1024), 0, stream>>>(Whh, b_hh, done, (const uint32_t*)gi_rz, xgi);
  k_heads<<<dim3(2048), dim3(256), 0, stream>>>(xgi, headW_h, pol_b, val_b, outp);
}